// Round 5
// baseline (10150.944 us; speedup 1.0000x reference)
//
#include <hip/hip_runtime.h>
#include <math.h>

#define N_NODES 10000
#define N_EDGES 320000
#define GRID 250
#define BLOCK 512
#define WPB 8            // waves per block
#define NPW 5            // nodes per wave
#define NPB 40           // nodes per block
#define ECAP 2048        // LDS edge cache (mean 1280/block, +21 sigma)

// ---------------- cross-block store: agent-scope write-through ----------------
// Never creates dirty L2 lines -> immune to buffer_inv dirty-drop; visible at
// L3 once vmcnt drains. (R2-proven write path.)
__device__ __forceinline__ void ast(float* p, float v) {
    __hip_atomic_store(p, v, __ATOMIC_RELAXED, __HIP_MEMORY_SCOPE_AGENT);
}

// ---------------- grid barrier ----------------
// Release: every thread's fence drains its wave's outstanding (write-through)
// stores; __syncthreads joins waves. Signal: lane0 agent atomics. Acquire:
// lane0 fence emits buffer_inv (invalidate L1 + XCD L2) so post-barrier plain
// loads refetch fresh data from L3 and re-cache it.
__device__ __forceinline__ void gbar(int* bar) {
    __builtin_amdgcn_fence(__ATOMIC_RELEASE, "workgroup");  // s_waitcnt vmcnt(0)
    __syncthreads();
    if (threadIdx.x == 0) {
        int* ctr = bar;
        int* gen = bar + 64;
        int g = __hip_atomic_load(gen, __ATOMIC_RELAXED, __HIP_MEMORY_SCOPE_AGENT);
        int a = __hip_atomic_fetch_add(ctr, 1, __ATOMIC_RELEASE, __HIP_MEMORY_SCOPE_AGENT);
        if (a == GRID - 1) {
            __hip_atomic_store(ctr, 0, __ATOMIC_RELAXED, __HIP_MEMORY_SCOPE_AGENT);
            __hip_atomic_store(gen, g + 1, __ATOMIC_RELEASE, __HIP_MEMORY_SCOPE_AGENT);
        } else {
            while (__hip_atomic_load(gen, __ATOMIC_RELAXED, __HIP_MEMORY_SCOPE_AGENT) == g)
                __builtin_amdgcn_s_sleep(1);
        }
        __builtin_amdgcn_fence(__ATOMIC_ACQUIRE, "agent");  // buffer_inv L1+L2
    }
    __syncthreads();
}

// ---------------- setup kernels ----------------
__global__ void k_init(float* deg, int* cnt, int* fill, int* bar, int n) {
    int i = blockIdx.x * blockDim.x + threadIdx.x;
    if (i < n) { deg[i] = 0.f; cnt[i] = 0; fill[i] = 0; }
    if (i < 128) bar[i] = 0;
}

__global__ void k_deg(const int* __restrict__ ei, const float* __restrict__ w,
                      float* deg, int E) {
    int e = blockIdx.x * blockDim.x + threadIdx.x;
    if (e < E) atomicAdd(&deg[ei[e]], w[e]);
}

__global__ void k_dis(float* deg, int n) {
    int i = blockIdx.x * blockDim.x + threadIdx.x;
    if (i < n) {
        float d = deg[i];
        deg[i] = (d > 0.f) ? (float)(1.0 / sqrt((double)d)) : 0.f;
    }
}

__global__ void k_norm(const int* __restrict__ ei, const float* __restrict__ w,
                       const float* __restrict__ dis, float* __restrict__ normw,
                       int* cnt, int E) {
    int e = blockIdx.x * blockDim.x + threadIdx.x;
    if (e < E) {
        int s = ei[e], d = ei[E + e];
        normw[e] = -dis[s] * w[e] * dis[d];
        atomicAdd(&cnt[d], 1);
    }
}

__global__ void k_scan(const int* __restrict__ cnt, int* __restrict__ rowptr, int n) {
    __shared__ int part[1024];
    const int PER = 10;
    int t = threadIdx.x;
    int base = t * PER;
    int local[PER];
    int s = 0;
    for (int j = 0; j < PER; j++) {
        int idx = base + j;
        int v = (idx < n) ? cnt[idx] : 0;
        local[j] = v; s += v;
    }
    part[t] = s;
    __syncthreads();
    for (int off = 1; off < 1024; off <<= 1) {
        int v = part[t];
        int u = (t >= off) ? part[t - off] : 0;
        __syncthreads();
        part[t] = v + u;
        __syncthreads();
    }
    int excl = (t > 0) ? part[t - 1] : 0;
    for (int j = 0; j < PER; j++) {
        int idx = base + j;
        if (idx < n) rowptr[idx] = excl;
        excl += local[j];
    }
    if (t == 1023) rowptr[n] = part[1023];
}

// pair CSR: {src byte-offset for stride-64 rows (src<<8), norm bits}
__global__ void k_fill(const int* __restrict__ ei, const float* __restrict__ normw,
                       const int* __restrict__ rowptr, int* fill,
                       int2* __restrict__ pr, int E) {
    int e = blockIdx.x * blockDim.x + threadIdx.x;
    if (e < E) {
        int d = ei[E + e];
        int pos = atomicAdd(&fill[d], 1);
        int idx = rowptr[d] + pos;
        pr[idx] = make_int2(ei[e] << 8, __float_as_int(normw[e]));
    }
}

// ---------------- gathers (plain cached loads, batch-8 pipelined) ----------------
template <bool L>
__device__ __forceinline__ float gather_w(const char* __restrict__ tb,
                                          const int2* ls_pr,
                                          const int2* __restrict__ g_pr,
                                          int rb, int dg, int lane4) {
    float agg = 0.f;
    int e = 0;
    for (; e + 8 <= dg; e += 8) {
        int2 p[8]; float v[8];
#pragma unroll
        for (int u = 0; u < 8; u++) p[u] = L ? ls_pr[rb + e + u] : g_pr[rb + e + u];
#pragma unroll
        for (int u = 0; u < 8; u++)
            v[u] = *(const float*)(tb + (unsigned)p[u].x + lane4);
#pragma unroll
        for (int u = 0; u < 8; u++)
            agg = fmaf(__int_as_float(p[u].y), v[u], agg);
    }
    if (e < dg) {  // masked batch-8 tail
        int2 p[8]; float v[8];
#pragma unroll
        for (int u = 0; u < 8; u++) {
            int idx = (e + u < dg) ? (rb + e + u) : rb;
            p[u] = L ? ls_pr[idx] : g_pr[idx];
        }
#pragma unroll
        for (int u = 0; u < 8; u++)
            v[u] = *(const float*)(tb + (unsigned)p[u].x + lane4);
#pragma unroll
        for (int u = 0; u < 8; u++) {
            float w = (e + u < dg) ? __int_as_float(p[u].y) : 0.f;
            agg = fmaf(w, v[u], agg);
        }
    }
    return agg;
}

// narrow (stride-4 rows): lane = eo*4+lc, 16 edges in parallel
template <bool L>
__device__ __forceinline__ float gather_n(const char* __restrict__ tb,
                                          const int2* ls_pr,
                                          const int2* __restrict__ g_pr,
                                          int rb, int dg, int lc4, int eo) {
    float agg = 0.f;
    int e = eo;
    for (; e + 32 <= dg; e += 32) {
        int2 p0 = L ? ls_pr[rb + e]      : g_pr[rb + e];
        int2 p1 = L ? ls_pr[rb + e + 16] : g_pr[rb + e + 16];
        float v0 = *(const float*)(tb + ((unsigned)p0.x >> 4) + lc4);
        float v1 = *(const float*)(tb + ((unsigned)p1.x >> 4) + lc4);
        agg = fmaf(__int_as_float(p0.y), v0, agg);
        agg = fmaf(__int_as_float(p1.y), v1, agg);
    }
    for (; e < dg; e += 16) {
        int2 p = L ? ls_pr[rb + e] : g_pr[rb + e];
        agg = fmaf(__int_as_float(p.y),
                   *(const float*)(tb + ((unsigned)p.x >> 4) + lc4), agg);
    }
    agg += __shfl_xor(agg, 4);
    agg += __shfl_xor(agg, 8);
    agg += __shfl_xor(agg, 16);
    agg += __shfl_xor(agg, 32);
    return agg;  // full sum for channel lc, replicated across eo groups
}

// ---------------- dense: acc(lane=o) += sum_c t2(c) * W[c][o] ----------------
template <int CI, int CO>
__device__ __forceinline__ void dense_step(float (&acc)[NPW], const float (&t2v)[NPW],
                                           const float* lsW, int lane)
{
#pragma unroll
    for (int c = 0; c < CI; c++) {
        float wv = lsW[c * CO + lane];   // lane>=CO: garbage, discarded at epilogue
#pragma unroll
        for (int j = 0; j < NPW; j++)
            acc[j] = fmaf(__shfl(t2v[j], c), wv, acc[j]);
    }
}

__device__ __forceinline__ void stage_w(const float* __restrict__ Wg, float* lsW, int cnt) {
    for (int i = threadIdx.x; i < cnt; i += BLOCK) lsW[i] = Wg[i];
}

// ---------------- one ChebConv layer ----------------
template <int CI, int CO, int K, int ACT, bool PUB>
__device__ void run_layer(
    float (&t1r)[NPW],
    const float* __restrict__ Wg, const float* __restrict__ bg,
    const float* __restrict__ hprev,
    float* tb0, float* tb1,
    float* __restrict__ hout,
    const int (&nodes)[NPW], const int (&rbj)[NPW], const int (&dgj)[NPW],
    bool use_lds, const int2* ls_pr, const int2* __restrict__ g_pr,
    float* lsW, int* bar, int lane)
{
    float t0r[NPW], acc[NPW];
    // ---- k = 0: acc = b + h @ W0 ----
    __syncthreads();
    stage_w(Wg, lsW, CI * CO);
    float bv = (bg != nullptr && lane < CO) ? bg[lane] : 0.f;
    __syncthreads();
#pragma unroll
    for (int j = 0; j < NPW; j++) { acc[j] = bv; t0r[j] = t1r[j]; }
    dense_step<CI, CO>(acc, t1r, lsW, lane);

    float* tb[2] = {tb0, tb1};
    int cur = 1;
    int eo = lane >> 2, lc4 = (lane & 3) * 4, lane4 = lane * 4;

#pragma unroll 1
    for (int k = 1; k < K; k++) {
        __syncthreads();
        stage_w(Wg + k * CI * CO, lsW, CI * CO);
        const char* gs = (const char*)((k == 1) ? hprev : tb[cur]);
        float t2v[NPW];
#pragma unroll
        for (int j = 0; j < NPW; j++) {
            float agg;
            if (CI == 4) {
                agg = use_lds
                    ? gather_n<true >(gs, ls_pr, g_pr, rbj[j], dgj[j], lc4, eo)
                    : gather_n<false>(gs, ls_pr, g_pr, rbj[j], dgj[j], lc4, eo);
            } else {
                agg = use_lds
                    ? gather_w<true >(gs, ls_pr, g_pr, rbj[j], dgj[j], lane4)
                    : gather_w<false>(gs, ls_pr, g_pr, rbj[j], dgj[j], lane4);
            }
            float t2 = (k == 1) ? agg : fmaf(2.f, agg, -t0r[j]);
            if (CI != 4 && lane >= CI) t2 = 0.f;
            t2v[j] = t2;
        }
        __syncthreads();
        dense_step<CI, CO>(acc, t2v, lsW, lane);
#pragma unroll
        for (int j = 0; j < NPW; j++) { t0r[j] = t1r[j]; t1r[j] = t2v[j]; }
        if (k < K - 1) {
            float* gd = tb[cur ^ 1];
#pragma unroll
            for (int j = 0; j < NPW; j++) {
                if (CI == 4) {
                    if (lane < 4) ast(&gd[nodes[j] * 4 + lane], t2v[j]);
                } else {
                    ast(&gd[nodes[j] * 64 + lane], t2v[j]);
                }
            }
            cur ^= 1;
            gbar(bar);
        }
    }
    // ---- epilogue ----
#pragma unroll
    for (int j = 0; j < NPW; j++) {
        float a = acc[j];
        float h = (ACT == 1) ? a / (1.f + expf(-a)) : a;
        if (lane >= CO) h = 0.f;
        t1r[j] = h;
    }
    if (PUB) {
#pragma unroll
        for (int j = 0; j < NPW; j++) ast(&hout[nodes[j] * 64 + lane], t1r[j]);
        gbar(bar);
    }
}

// ---------------- persistent kernel: all 4 layers, ~257 grid barriers ----------------
__global__ __launch_bounds__(BLOCK, 2) void persistent(
    const float* __restrict__ x,
    const int* __restrict__ rowptr, const int2* __restrict__ g_pr,
    const float* __restrict__ W1, const float* __restrict__ b1,
    const float* __restrict__ W2, const float* __restrict__ b2,
    const float* __restrict__ W3, const float* __restrict__ b3,
    const float* __restrict__ W4,
    float* t4a, float* t4b, float* tba, float* tbb,
    float* h1, float* h2, float* out, int* bar)
{
    __shared__ int2  ls_pr[ECAP];   // 16 KB: block's CSR slice, reused all steps
    __shared__ float lsW[4096];     // 16 KB: current Wk

    int tid = threadIdx.x;
    int w = tid >> 6, lane = tid & 63;

    int nb0 = blockIdx.x * NPB;
    int eb = rowptr[nb0];
    int ee = rowptr[nb0 + NPB];
    int ecnt = ee - eb;
    bool use_lds = (ecnt <= ECAP);
    if (use_lds) {
        for (int i = tid; i < ecnt; i += BLOCK) ls_pr[i] = g_pr[eb + i];
    }

    int nodes[NPW], rbj[NPW], dgj[NPW];
    int node0 = nb0 + w * NPW;
#pragma unroll
    for (int j = 0; j < NPW; j++) {
        nodes[j] = node0 + j;
        int r0 = rowptr[nodes[j]], r1 = rowptr[nodes[j] + 1];
        dgj[j] = r1 - r0;
        rbj[j] = use_lds ? (r0 - eb) : r0;
    }
    __syncthreads();

    float t1r[NPW];
#pragma unroll
    for (int j = 0; j < NPW; j++) t1r[j] = x[nodes[j] * 4 + (lane & 3)];

    // Layer 1: K=120, 4->64, silu
    run_layer<4, 64, 120, 1, true>(t1r, W1, b1, x, t4a, t4b, h1,
                                   nodes, rbj, dgj, use_lds, ls_pr, g_pr,
                                   lsW, bar, lane);
    // Layer 2: K=120, 64->60, silu
    run_layer<64, 60, 120, 1, true>(t1r, W2, b2, h1, tba, tbb, h2,
                                    nodes, rbj, dgj, use_lds, ls_pr, g_pr,
                                    lsW, bar, lane);
    // Layer 3: K=20, 60->30, silu (output stays in registers)
    run_layer<60, 30, 20, 1, false>(t1r, W3, b3, h2, tba, tbb, nullptr,
                                    nodes, rbj, dgj, use_lds, ls_pr, g_pr,
                                    lsW, bar, lane);

    // Layer 4: K=1, 30->1, sigmoid
    float w4 = (lane < 30) ? W4[lane] : 0.f;
#pragma unroll
    for (int j = 0; j < NPW; j++) {
        float p = t1r[j] * w4;
        p += __shfl_xor(p, 1);
        p += __shfl_xor(p, 2);
        p += __shfl_xor(p, 4);
        p += __shfl_xor(p, 8);
        p += __shfl_xor(p, 16);
        p += __shfl_xor(p, 32);
        if (lane == 0) out[nodes[j]] = 1.f / (1.f + expf(-p));
    }
}

// ---------------- host ----------------
extern "C" void kernel_launch(void* const* d_in, const int* in_sizes, int n_in,
                              void* d_out, int out_size, void* d_ws, size_t ws_size,
                              hipStream_t stream) {
    const float* x  = (const float*)d_in[0];
    const int*   ei = (const int*)d_in[1];
    const float* ew = (const float*)d_in[2];
    const float* W1 = (const float*)d_in[3];
    const float* b1 = (const float*)d_in[4];
    const float* W2 = (const float*)d_in[5];
    const float* b2 = (const float*)d_in[6];
    const float* W3 = (const float*)d_in[7];
    const float* b3 = (const float*)d_in[8];
    const float* W4 = (const float*)d_in[9];
    float* out = (float*)d_out;

    const int n = N_NODES, E = N_EDGES;

    char* ws = (char*)d_ws;
    size_t off = 0;
    auto alloc = [&](size_t bytes) -> void* {
        void* p = ws + off;
        off += (bytes + 255) & ~(size_t)255;
        return p;
    };
    float* deg    = (float*)alloc(n * 4);
    int*   cnt    = (int*)alloc(n * 4);
    int*   fill   = (int*)alloc(n * 4);
    int*   rowptr = (int*)alloc((n + 4) * 4);
    float* normw  = (float*)alloc((size_t)E * 4);
    int2*  pr     = (int2*)alloc((size_t)E * 8);
    int*   bar    = (int*)alloc(128 * 4);
    float* t4a = (float*)alloc(n * 4 * 4);
    float* t4b = (float*)alloc(n * 4 * 4);
    float* tba = (float*)alloc(n * 64 * 4);
    float* tbb = (float*)alloc(n * 64 * 4);
    float* h1  = (float*)alloc(n * 64 * 4);
    float* h2  = (float*)alloc(n * 64 * 4);
    (void)ws_size; (void)n_in; (void)in_sizes; (void)out_size;

    k_init<<<(n + 255) / 256, 256, 0, stream>>>(deg, cnt, fill, bar, n);
    k_deg <<<(E + 255) / 256, 256, 0, stream>>>(ei, ew, deg, E);
    k_dis <<<(n + 255) / 256, 256, 0, stream>>>(deg, n);
    k_norm<<<(E + 255) / 256, 256, 0, stream>>>(ei, ew, deg, normw, cnt, E);
    k_scan<<<1, 1024, 0, stream>>>(cnt, rowptr, n);
    k_fill<<<(E + 255) / 256, 256, 0, stream>>>(ei, normw, rowptr, fill, pr, E);

    persistent<<<GRID, BLOCK, 0, stream>>>(
        x, rowptr, pr,
        W1, b1, W2, b2, W3, b3, W4,
        t4a, t4b, tba, tbb, h1, h2, out, bar);
}

// Round 6
// 10003.552 us; speedup vs baseline: 1.0147x; 1.0147x over previous
//
#include <hip/hip_runtime.h>
#include <math.h>

#define N_NODES 10000
#define N_EDGES 320000
#define GRID 250
#define BLOCK 512
#define NPW 5            // nodes per wave
#define NPB 40           // nodes per block (8 waves * 5)
#define ECAP 2048        // LDS edge cache (mean 1280/block; max@250 blocks ~1450)

typedef float v4f __attribute__((ext_vector_type(4)));

// 16B write-through store, device-visible (never dirty in L2). Coalesced:
// 4 consecutive lanes = one full 64B line.
__device__ __forceinline__ void store16_wt(float* p, v4f v) {
    asm volatile("global_store_dwordx4 %0, %1, off sc0 sc1"
                 :: "v"(p), "v"(v) : "memory");
}

// ---------------- grid barrier (R5-proven) ----------------
__device__ __forceinline__ void gbar(int* bar) {
    __builtin_amdgcn_fence(__ATOMIC_RELEASE, "workgroup");  // drain vmcnt
    __syncthreads();
    if (threadIdx.x == 0) {
        int* ctr = bar;
        int* gen = bar + 64;
        int g = __hip_atomic_load(gen, __ATOMIC_RELAXED, __HIP_MEMORY_SCOPE_AGENT);
        int a = __hip_atomic_fetch_add(ctr, 1, __ATOMIC_RELEASE, __HIP_MEMORY_SCOPE_AGENT);
        if (a == GRID - 1) {
            __hip_atomic_store(ctr, 0, __ATOMIC_RELAXED, __HIP_MEMORY_SCOPE_AGENT);
            __hip_atomic_store(gen, g + 1, __ATOMIC_RELEASE, __HIP_MEMORY_SCOPE_AGENT);
        } else {
            while (__hip_atomic_load(gen, __ATOMIC_RELAXED, __HIP_MEMORY_SCOPE_AGENT) == g)
                __builtin_amdgcn_s_sleep(1);
        }
        __builtin_amdgcn_fence(__ATOMIC_ACQUIRE, "agent");  // buffer_inv (L1+L2)
    }
    __syncthreads();
}

// ---------------- setup kernels ----------------
__global__ void k_init(float* deg, int* cnt, int* fill, int* bar, int n) {
    int i = blockIdx.x * blockDim.x + threadIdx.x;
    if (i < n) { deg[i] = 0.f; cnt[i] = 0; fill[i] = 0; }
    if (i < 128) bar[i] = 0;
}

__global__ void k_deg(const int* __restrict__ ei, const float* __restrict__ w,
                      float* deg, int E) {
    int e = blockIdx.x * blockDim.x + threadIdx.x;
    if (e < E) atomicAdd(&deg[ei[e]], w[e]);
}

__global__ void k_dis(float* deg, int n) {
    int i = blockIdx.x * blockDim.x + threadIdx.x;
    if (i < n) {
        float d = deg[i];
        deg[i] = (d > 0.f) ? (float)(1.0 / sqrt((double)d)) : 0.f;
    }
}

__global__ void k_norm(const int* __restrict__ ei, const float* __restrict__ w,
                       const float* __restrict__ dis, float* __restrict__ normw,
                       int* cnt, int E) {
    int e = blockIdx.x * blockDim.x + threadIdx.x;
    if (e < E) {
        int s = ei[e], d = ei[E + e];
        normw[e] = -dis[s] * w[e] * dis[d];
        atomicAdd(&cnt[d], 1);
    }
}

__global__ void k_scan(const int* __restrict__ cnt, int* __restrict__ rowptr, int n) {
    __shared__ int part[1024];
    const int PER = 10;
    int t = threadIdx.x;
    int base = t * PER;
    int local[PER];
    int s = 0;
    for (int j = 0; j < PER; j++) {
        int idx = base + j;
        int v = (idx < n) ? cnt[idx] : 0;
        local[j] = v; s += v;
    }
    part[t] = s;
    __syncthreads();
    for (int off = 1; off < 1024; off <<= 1) {
        int v = part[t];
        int u = (t >= off) ? part[t - off] : 0;
        __syncthreads();
        part[t] = v + u;
        __syncthreads();
    }
    int excl = (t > 0) ? part[t - 1] : 0;
    for (int j = 0; j < PER; j++) {
        int idx = base + j;
        if (idx < n) rowptr[idx] = excl;
        excl += local[j];
    }
    if (t == 1023) rowptr[n] = part[1023];
}

// pair CSR: {src byte-offset for stride-64 rows (src<<8), norm bits}
__global__ void k_fill(const int* __restrict__ ei, const float* __restrict__ normw,
                       const int* __restrict__ rowptr, int* fill,
                       int2* __restrict__ pr, int E) {
    int e = blockIdx.x * blockDim.x + threadIdx.x;
    if (e < E) {
        int d = ei[E + e];
        int pos = atomicAdd(&fill[d], 1);
        int idx = rowptr[d] + pos;
        pr[idx] = make_int2(ei[e] << 8, __float_as_int(normw[e]));
    }
}

// ---------------- gathers, float4-per-lane layout ----------------
// wide (256B rows): lane = (g, q), g=lane>>4 edge-in-group, q=lane&15 quad.
// 4 edges per load instruction; result: channels 4q..4q+3, replicated over g.
template <bool L>
__device__ __forceinline__ v4f gather_w4(const char* __restrict__ tb,
                                         const int2* ls_pr,
                                         const int2* __restrict__ g_pr,
                                         int rb, int dg, int g, int q16) {
    v4f agg = {0.f, 0.f, 0.f, 0.f};
    int eb = 0;
    for (; eb + 32 <= dg; eb += 32) {  // 32 edges in flight (8 instrs)
        int2 p[8]; v4f v[8];
#pragma unroll
        for (int u = 0; u < 8; u++) {
            int idx = rb + eb + 4 * u + g;
            p[u] = L ? ls_pr[idx] : g_pr[idx];
        }
#pragma unroll
        for (int u = 0; u < 8; u++)
            v[u] = *(const v4f*)(tb + (unsigned)p[u].x + q16);
#pragma unroll
        for (int u = 0; u < 8; u++)
            agg += __int_as_float(p[u].y) * v[u];
    }
    if (eb < dg) {  // masked batch tail
        int2 p[8]; v4f v[8];
#pragma unroll
        for (int u = 0; u < 8; u++) {
            int idx = eb + 4 * u + g;
            p[u] = L ? ls_pr[(idx < dg) ? (rb + idx) : rb]
                     : g_pr[(idx < dg) ? (rb + idx) : rb];
        }
#pragma unroll
        for (int u = 0; u < 8; u++)
            v[u] = *(const v4f*)(tb + (unsigned)p[u].x + q16);
#pragma unroll
        for (int u = 0; u < 8; u++) {
            int idx = eb + 4 * u + g;
            float wv = (idx < dg) ? __int_as_float(p[u].y) : 0.f;
            agg += wv * v[u];
        }
    }
    agg.x += __shfl_xor(agg.x, 16); agg.y += __shfl_xor(agg.y, 16);
    agg.z += __shfl_xor(agg.z, 16); agg.w += __shfl_xor(agg.w, 16);
    agg.x += __shfl_xor(agg.x, 32); agg.y += __shfl_xor(agg.y, 32);
    agg.z += __shfl_xor(agg.z, 32); agg.w += __shfl_xor(agg.w, 32);
    return agg;
}

// narrow (16B rows): lane = edge, full row per lane, butterfly over 64 lanes.
template <bool L>
__device__ __forceinline__ v4f gather_n4(const char* __restrict__ tb,
                                         const int2* ls_pr,
                                         const int2* __restrict__ g_pr,
                                         int rb, int dg, int lane) {
    v4f agg = {0.f, 0.f, 0.f, 0.f};
    for (int eb = 0; eb < dg; eb += 64) {
        int idx = eb + lane;
        int cl = (idx < dg) ? idx : (dg - 1);
        int2 p = L ? ls_pr[rb + cl] : g_pr[rb + cl];
        float wv = (idx < dg) ? __int_as_float(p.y) : 0.f;
        v4f v = *(const v4f*)(tb + ((unsigned)p.x >> 4));
        agg += wv * v;
    }
#pragma unroll
    for (int m = 1; m <= 32; m <<= 1) {
        agg.x += __shfl_xor(agg.x, m); agg.y += __shfl_xor(agg.y, m);
        agg.z += __shfl_xor(agg.z, m); agg.w += __shfl_xor(agg.w, m);
    }
    return agg;
}

// ---------------- dense: acc(lane=o) += sum_c t(c) * W[c][o] ----------------
// t in f4-replicated layout: channel 4*c4+i = component i of lane c4.
template <int CI, int CO>
__device__ __forceinline__ void dense_f4(float (&acc)[NPW], const v4f (&t)[NPW],
                                         const float* lsW, int lane) {
#pragma unroll
    for (int c4 = 0; c4 < CI / 4; c4++) {
        float w0 = lsW[(4 * c4 + 0) * CO + lane];
        float w1 = lsW[(4 * c4 + 1) * CO + lane];
        float w2 = lsW[(4 * c4 + 2) * CO + lane];
        float w3 = lsW[(4 * c4 + 3) * CO + lane];
#pragma unroll
        for (int j = 0; j < NPW; j++) {
            acc[j] = fmaf(__shfl(t[j].x, c4), w0, acc[j]);
            acc[j] = fmaf(__shfl(t[j].y, c4), w1, acc[j]);
            acc[j] = fmaf(__shfl(t[j].z, c4), w2, acc[j]);
            acc[j] = fmaf(__shfl(t[j].w, c4), w3, acc[j]);
        }
    }
}

__device__ __forceinline__ void stage_w(const float* __restrict__ Wg, float* lsW, int cnt) {
    for (int i = threadIdx.x; i < cnt; i += BLOCK) lsW[i] = Wg[i];
}

// wide rows (n x 64): groups 0-3 store nodes 0-3, group 0 also node 4
__device__ __forceinline__ void rows64_store(float* base, int node0,
                                             const v4f (&v)[NPW], int lane) {
    int g = lane >> 4, q = lane & 15;
    v4f sv = v[0];
    if (g == 1) sv = v[1];
    if (g == 2) sv = v[2];
    if (g == 3) sv = v[3];
    store16_wt(base + (node0 + g) * 64 + q * 4, sv);
    if (g == 0) store16_wt(base + (node0 + 4) * 64 + q * 4, v[4]);
}

// narrow rows (n x 4): lane j stores node j
__device__ __forceinline__ void rows4_store(float* base, int node0,
                                            const v4f (&v)[NPW], int lane) {
#pragma unroll
    for (int j = 0; j < NPW; j++)
        if (lane == j) store16_wt(base + (node0 + j) * 4, v[j]);
}

// ---------------- one ChebConv layer ----------------
// hq in: input features in f4-replicated layout. acc out: pre-activation,
// lane = out-channel. NARROW selects 16B-row gather/store path.
template <int CI, int CO, int K, bool NARROW>
__device__ void cheb_layer(
    v4f (&hq)[NPW], float (&acc)[NPW],
    const float* __restrict__ Wg, const float* __restrict__ bg,
    const float* __restrict__ hprev,
    float* tb0, float* tb1,
    int node0, const int (&rbj)[NPW], const int (&dgj)[NPW],
    bool use_lds, const int2* ls_pr, const int2* __restrict__ g_pr,
    float* lsW, int* bar, int lane)
{
    int g = lane >> 4, q16 = (lane & 15) * 16;
    v4f t0r[NPW], t1r[NPW];

    // ---- k = 0 ----
    __syncthreads();
    stage_w(Wg, lsW, CI * CO);
    float bv = (bg != nullptr && lane < CO) ? bg[lane] : 0.f;
    __syncthreads();
#pragma unroll
    for (int j = 0; j < NPW; j++) { acc[j] = bv; t0r[j] = hq[j]; t1r[j] = hq[j]; }
    dense_f4<CI, CO>(acc, hq, lsW, lane);

    float* tb[2] = {tb0, tb1};
    int cur = 1;

#pragma unroll 1
    for (int k = 1; k < K; k++) {
        __syncthreads();
        stage_w(Wg + k * CI * CO, lsW, CI * CO);
        const char* gs = (const char*)((k == 1) ? hprev : tb[cur]);
        v4f t2[NPW];
#pragma unroll
        for (int j = 0; j < NPW; j++) {
            v4f a;
            if (NARROW) {
                a = use_lds
                    ? gather_n4<true >(gs, ls_pr, g_pr, rbj[j], dgj[j], lane)
                    : gather_n4<false>(gs, ls_pr, g_pr, rbj[j], dgj[j], lane);
            } else {
                a = use_lds
                    ? gather_w4<true >(gs, ls_pr, g_pr, rbj[j], dgj[j], g, q16)
                    : gather_w4<false>(gs, ls_pr, g_pr, rbj[j], dgj[j], g, q16);
            }
            t2[j] = (k == 1) ? a : (2.f * a - t0r[j]);
        }
        if (k < K - 1) {  // publish T_k for other blocks' next-step gathers
            float* gd = tb[cur ^ 1];
            if (NARROW) rows4_store(gd, node0, t2, lane);
            else        rows64_store(gd, node0, t2, lane);
        }
        __syncthreads();
        dense_f4<CI, CO>(acc, t2, lsW, lane);
#pragma unroll
        for (int j = 0; j < NPW; j++) {
            v4f tmp = t1r[j];
            t1r[j] = t2[j];
            if (k >= 2) t0r[j] = tmp;
        }
        cur ^= 1;
        if (k < K - 1) gbar(bar);
    }
}

// ---------------- persistent kernel ----------------
__global__ __launch_bounds__(BLOCK, 2) void persistent(
    const float* __restrict__ x,
    const int* __restrict__ rowptr, const int2* __restrict__ g_pr,
    const float* __restrict__ W1, const float* __restrict__ b1,
    const float* __restrict__ W2, const float* __restrict__ b2,
    const float* __restrict__ W3, const float* __restrict__ b3,
    const float* __restrict__ W4,
    float* t4a, float* t4b, float* tba, float* tbb,
    float* h1, float* h2, float* out, int* bar)
{
    __shared__ int2  ls_pr[ECAP];   // 16 KB CSR slice, reused all 257 steps
    __shared__ float lsW[4096];     // 16 KB current Wk

    int tid = threadIdx.x;
    int w = tid >> 6, lane = tid & 63;

    int nb0 = blockIdx.x * NPB;
    int eb = rowptr[nb0];
    int ee = rowptr[nb0 + NPB];
    int ecnt = ee - eb;
    bool use_lds = (ecnt <= ECAP);
    if (use_lds) {
        for (int i = tid; i < ecnt; i += BLOCK) ls_pr[i] = g_pr[eb + i];
    }

    int rbj[NPW], dgj[NPW];
    int node0 = nb0 + w * NPW;
#pragma unroll
    for (int j = 0; j < NPW; j++) {
        int r0 = rowptr[node0 + j], r1 = rowptr[node0 + j + 1];
        dgj[j] = r1 - r0;
        rbj[j] = use_lds ? (r0 - eb) : r0;
    }
    __syncthreads();

    v4f hq[NPW];
    float acc[NPW];
#pragma unroll
    for (int j = 0; j < NPW; j++) hq[j] = *(const v4f*)(x + (node0 + j) * 4);

    // ---- Layer 1: K=120, 4->64, silu ----
    cheb_layer<4, 64, 120, true>(hq, acc, W1, b1, x, t4a, t4b,
                                 node0, rbj, dgj, use_lds, ls_pr, g_pr,
                                 lsW, bar, lane);
    {   // epilogue: silu -> f4 layout -> publish h1
        int q = lane & 15;
#pragma unroll
        for (int j = 0; j < NPW; j++) {
            float a = acc[j];
            float h = a / (1.f + expf(-a));
            hq[j].x = __shfl(h, 4 * q + 0);
            hq[j].y = __shfl(h, 4 * q + 1);
            hq[j].z = __shfl(h, 4 * q + 2);
            hq[j].w = __shfl(h, 4 * q + 3);
        }
        rows64_store(h1, node0, hq, lane);
        gbar(bar);
    }

    // ---- Layer 2: K=120, 64->60, silu ----
    cheb_layer<64, 60, 120, false>(hq, acc, W2, b2, h1, tba, tbb,
                                   node0, rbj, dgj, use_lds, ls_pr, g_pr,
                                   lsW, bar, lane);
    {   // epilogue: silu, zero ch>=60, publish h2
        int q = lane & 15;
#pragma unroll
        for (int j = 0; j < NPW; j++) {
            float a = acc[j];
            float h = a / (1.f + expf(-a));
            if (lane >= 60) h = 0.f;
            hq[j].x = __shfl(h, 4 * q + 0);
            hq[j].y = __shfl(h, 4 * q + 1);
            hq[j].z = __shfl(h, 4 * q + 2);
            hq[j].w = __shfl(h, 4 * q + 3);
        }
        rows64_store(h2, node0, hq, lane);
        gbar(bar);
    }

    // ---- Layer 3: K=20, 60->30, silu (stays in registers) ----
    cheb_layer<60, 30, 20, false>(hq, acc, W3, b3, h2, tba, tbb,
                                  node0, rbj, dgj, use_lds, ls_pr, g_pr,
                                  lsW, bar, lane);

    // ---- Layer 4: K=1, 30->1, sigmoid ----
    float w4 = (lane < 30) ? W4[lane] : 0.f;
#pragma unroll
    for (int j = 0; j < NPW; j++) {
        float a = acc[j];
        float h = a / (1.f + expf(-a));
        if (lane >= 30) h = 0.f;
        float p = h * w4;
        p += __shfl_xor(p, 1);
        p += __shfl_xor(p, 2);
        p += __shfl_xor(p, 4);
        p += __shfl_xor(p, 8);
        p += __shfl_xor(p, 16);
        p += __shfl_xor(p, 32);
        if (lane == 0) out[node0 + j] = 1.f / (1.f + expf(-p));
    }
}

// ---------------- host ----------------
extern "C" void kernel_launch(void* const* d_in, const int* in_sizes, int n_in,
                              void* d_out, int out_size, void* d_ws, size_t ws_size,
                              hipStream_t stream) {
    const float* x  = (const float*)d_in[0];
    const int*   ei = (const int*)d_in[1];
    const float* ew = (const float*)d_in[2];
    const float* W1 = (const float*)d_in[3];
    const float* b1 = (const float*)d_in[4];
    const float* W2 = (const float*)d_in[5];
    const float* b2 = (const float*)d_in[6];
    const float* W3 = (const float*)d_in[7];
    const float* b3 = (const float*)d_in[8];
    const float* W4 = (const float*)d_in[9];
    float* out = (float*)d_out;

    const int n = N_NODES, E = N_EDGES;

    char* ws = (char*)d_ws;
    size_t off = 0;
    auto alloc = [&](size_t bytes) -> void* {
        void* p = ws + off;
        off += (bytes + 255) & ~(size_t)255;
        return p;
    };
    float* deg    = (float*)alloc(n * 4);
    int*   cnt    = (int*)alloc(n * 4);
    int*   fill   = (int*)alloc(n * 4);
    int*   rowptr = (int*)alloc((n + 4) * 4);
    float* normw  = (float*)alloc((size_t)E * 4);
    int2*  pr     = (int2*)alloc((size_t)E * 8);
    int*   bar    = (int*)alloc(128 * 4);
    float* t4a = (float*)alloc(n * 4 * 4);
    float* t4b = (float*)alloc(n * 4 * 4);
    float* tba = (float*)alloc(n * 64 * 4);
    float* tbb = (float*)alloc(n * 64 * 4);
    float* h1  = (float*)alloc(n * 64 * 4);
    float* h2  = (float*)alloc(n * 64 * 4);
    (void)ws_size; (void)n_in; (void)in_sizes; (void)out_size;

    k_init<<<(n + 255) / 256, 256, 0, stream>>>(deg, cnt, fill, bar, n);
    k_deg <<<(E + 255) / 256, 256, 0, stream>>>(ei, ew, deg, E);
    k_dis <<<(n + 255) / 256, 256, 0, stream>>>(deg, n);
    k_norm<<<(E + 255) / 256, 256, 0, stream>>>(ei, ew, deg, normw, cnt, E);
    k_scan<<<1, 1024, 0, stream>>>(cnt, rowptr, n);
    k_fill<<<(E + 255) / 256, 256, 0, stream>>>(ei, normw, rowptr, fill, pr, E);

    persistent<<<GRID, BLOCK, 0, stream>>>(
        x, rowptr, pr,
        W1, b1, W2, b2, W3, b3, W4,
        t4a, t4b, tba, tbb, h1, h2, out, bar);
}

// Round 7
// 4121.708 us; speedup vs baseline: 2.4628x; 2.4270x over previous
//
#include <hip/hip_runtime.h>
#include <math.h>

#define N_NODES 10000
#define N_EDGES 320000
#define GRID 250
#define BLOCK 512
#define NPW 5            // nodes per wave (persistent layer-1)
#define NPB 40           // nodes per block
#define ECAP 2048        // LDS edge cache (mean 1280/block, max ~1450)

// ---------------- cross-block store: agent-scope write-through (R5-proven) ----
__device__ __forceinline__ void ast(float* p, float v) {
    __hip_atomic_store(p, v, __ATOMIC_RELAXED, __HIP_MEMORY_SCOPE_AGENT);
}

// ---------------- grid barrier (R5-proven) ----------------
__device__ __forceinline__ void gbar(int* bar) {
    __builtin_amdgcn_fence(__ATOMIC_RELEASE, "workgroup");  // drain vmcnt
    __syncthreads();
    if (threadIdx.x == 0) {
        int* ctr = bar;
        int* gen = bar + 64;
        int g = __hip_atomic_load(gen, __ATOMIC_RELAXED, __HIP_MEMORY_SCOPE_AGENT);
        int a = __hip_atomic_fetch_add(ctr, 1, __ATOMIC_RELEASE, __HIP_MEMORY_SCOPE_AGENT);
        if (a == GRID - 1) {
            __hip_atomic_store(ctr, 0, __ATOMIC_RELAXED, __HIP_MEMORY_SCOPE_AGENT);
            __hip_atomic_store(gen, g + 1, __ATOMIC_RELEASE, __HIP_MEMORY_SCOPE_AGENT);
        } else {
            while (__hip_atomic_load(gen, __ATOMIC_RELAXED, __HIP_MEMORY_SCOPE_AGENT) == g)
                __builtin_amdgcn_s_sleep(1);
        }
        __builtin_amdgcn_fence(__ATOMIC_ACQUIRE, "agent");  // buffer_inv (L1+L2)
    }
    __syncthreads();
}

// ---------------- setup kernels ----------------
__global__ void k_init(float* deg, int* cnt, int* fill, int* bar, int n) {
    int i = blockIdx.x * blockDim.x + threadIdx.x;
    if (i < n) { deg[i] = 0.f; cnt[i] = 0; fill[i] = 0; }
    if (i < 128) bar[i] = 0;
}

__global__ void k_deg(const int* __restrict__ ei, const float* __restrict__ w,
                      float* deg, int E) {
    int e = blockIdx.x * blockDim.x + threadIdx.x;
    if (e < E) atomicAdd(&deg[ei[e]], w[e]);
}

__global__ void k_dis(float* deg, int n) {
    int i = blockIdx.x * blockDim.x + threadIdx.x;
    if (i < n) {
        float d = deg[i];
        deg[i] = (d > 0.f) ? (float)(1.0 / sqrt((double)d)) : 0.f;
    }
}

__global__ void k_norm(const int* __restrict__ ei, const float* __restrict__ w,
                       const float* __restrict__ dis, float* __restrict__ normw,
                       int* cnt, int E) {
    int e = blockIdx.x * blockDim.x + threadIdx.x;
    if (e < E) {
        int s = ei[e], d = ei[E + e];
        normw[e] = -dis[s] * w[e] * dis[d];
        atomicAdd(&cnt[d], 1);
    }
}

__global__ void k_scan(const int* __restrict__ cnt, int* __restrict__ rowptr, int n) {
    __shared__ int part[1024];
    const int PER = 10;
    int t = threadIdx.x;
    int base = t * PER;
    int local[PER];
    int s = 0;
    for (int j = 0; j < PER; j++) {
        int idx = base + j;
        int v = (idx < n) ? cnt[idx] : 0;
        local[j] = v; s += v;
    }
    part[t] = s;
    __syncthreads();
    for (int off = 1; off < 1024; off <<= 1) {
        int v = part[t];
        int u = (t >= off) ? part[t - off] : 0;
        __syncthreads();
        part[t] = v + u;
        __syncthreads();
    }
    int excl = (t > 0) ? part[t - 1] : 0;
    for (int j = 0; j < PER; j++) {
        int idx = base + j;
        if (idx < n) rowptr[idx] = excl;
        excl += local[j];
    }
    if (t == 1023) rowptr[n] = part[1023];
}

// pair CSR: {src byte-offset for stride-64 rows (src<<8), norm bits}
__global__ void k_fill(const int* __restrict__ ei, const float* __restrict__ normw,
                       const int* __restrict__ rowptr, int* fill,
                       int2* __restrict__ pr, int E) {
    int e = blockIdx.x * blockDim.x + threadIdx.x;
    if (e < E) {
        int d = ei[E + e];
        int pos = atomicAdd(&fill[d], 1);
        int idx = rowptr[d] + pos;
        pr[idx] = make_int2(ei[e] << 8, __float_as_int(normw[e]));
    }
}

// ---------------- narrow gather (R5-proven): stride-4 rows, 16 edges parallel --
template <bool L>
__device__ __forceinline__ float gather_n(const char* __restrict__ tb,
                                          const int2* ls_pr,
                                          const int2* __restrict__ g_pr,
                                          int rb, int dg, int lc4, int eo) {
    float agg = 0.f;
    int e = eo;
    for (; e + 32 <= dg; e += 32) {
        int2 p0 = L ? ls_pr[rb + e]      : g_pr[rb + e];
        int2 p1 = L ? ls_pr[rb + e + 16] : g_pr[rb + e + 16];
        float v0 = *(const float*)(tb + ((unsigned)p0.x >> 4) + lc4);
        float v1 = *(const float*)(tb + ((unsigned)p1.x >> 4) + lc4);
        agg = fmaf(__int_as_float(p0.y), v0, agg);
        agg = fmaf(__int_as_float(p1.y), v1, agg);
    }
    for (; e < dg; e += 16) {
        int2 p = L ? ls_pr[rb + e] : g_pr[rb + e];
        agg = fmaf(__int_as_float(p.y),
                   *(const float*)(tb + ((unsigned)p.x >> 4) + lc4), agg);
    }
    agg += __shfl_xor(agg, 4);
    agg += __shfl_xor(agg, 8);
    agg += __shfl_xor(agg, 16);
    agg += __shfl_xor(agg, 32);
    return agg;  // full sum for channel lc, replicated across eo groups
}

// ---------------- wide gather (R3-proven): stride-64 rows, batch-8 -------------
__device__ __forceinline__ float gather_w(const char* __restrict__ tb,
                                          const int2* __restrict__ pr,
                                          int rb, int dg, int lane4) {
    float agg = 0.f;
    int e = 0;
    for (; e + 8 <= dg; e += 8) {
        int2 p[8]; float v[8];
#pragma unroll
        for (int u = 0; u < 8; u++) p[u] = pr[rb + e + u];
#pragma unroll
        for (int u = 0; u < 8; u++)
            v[u] = *(const float*)(tb + (unsigned)p[u].x + lane4);
#pragma unroll
        for (int u = 0; u < 8; u++)
            agg = fmaf(__int_as_float(p[u].y), v[u], agg);
    }
    if (e < dg) {
        int2 p[8]; float v[8];
#pragma unroll
        for (int u = 0; u < 8; u++) p[u] = pr[(e + u < dg) ? (rb + e + u) : rb];
#pragma unroll
        for (int u = 0; u < 8; u++)
            v[u] = *(const float*)(tb + (unsigned)p[u].x + lane4);
#pragma unroll
        for (int u = 0; u < 8; u++) {
            float w = (e + u < dg) ? __int_as_float(p[u].y) : 0.f;
            agg = fmaf(w, v[u], agg);
        }
    }
    return agg;
}

// ---------------- dense helpers ----------------
// persistent-kernel dense: LDS weights + shfl broadcast (R5-proven)
template <int CI, int CO>
__device__ __forceinline__ void dense_step(float (&acc)[NPW], const float (&t2v)[NPW],
                                           const float* lsW, int lane)
{
#pragma unroll
    for (int c = 0; c < CI; c++) {
        float wv = lsW[c * CO + lane];
#pragma unroll
        for (int j = 0; j < NPW; j++)
            acc[j] = fmaf(__shfl(t2v[j], c), wv, acc[j]);
    }
}

__device__ __forceinline__ void stage_w(const float* __restrict__ Wg, float* lsW, int cnt) {
    for (int i = threadIdx.x; i < cnt; i += BLOCK) lsW[i] = Wg[i];
}

// k_wide dense: readlane broadcast (R3-proven)
template <int CI, int CO>
__device__ __forceinline__ void dense(float& acc, float t2v,
                                      const float* __restrict__ Wk, int lane) {
#pragma unroll
    for (int c = 0; c < CI; c++) {
        float tb = __int_as_float(__builtin_amdgcn_readlane(__float_as_int(t2v), c));
        float wv;
        if (CO < 64) wv = (lane < CO) ? Wk[c * CO + lane] : 0.f;
        else         wv = Wk[c * CO + lane];
        acc = fmaf(tb, wv, acc);
    }
}

// ---------------- persistent layer 1: K=120, 4->64, silu -> h1 ----------------
__global__ __launch_bounds__(BLOCK, 2) void layer1_persistent(
    const float* __restrict__ x,
    const int* __restrict__ rowptr, const int2* __restrict__ g_pr,
    const float* __restrict__ W1, const float* __restrict__ b1,
    float* t4a, float* t4b, float* __restrict__ h1, int* bar)
{
    __shared__ int2  ls_pr[ECAP];
    __shared__ float lsW[4 * 64];

    const int K = 120, CI = 4, CO = 64;
    int tid = threadIdx.x;
    int w = tid >> 6, lane = tid & 63;

    int nb0 = blockIdx.x * NPB;
    int eb = rowptr[nb0];
    int ee = rowptr[nb0 + NPB];
    int ecnt = ee - eb;
    bool use_lds = (ecnt <= ECAP);
    if (use_lds) {
        for (int i = tid; i < ecnt; i += BLOCK) ls_pr[i] = g_pr[eb + i];
    }

    int nodes[NPW], rbj[NPW], dgj[NPW];
    int node0 = nb0 + w * NPW;
#pragma unroll
    for (int j = 0; j < NPW; j++) {
        nodes[j] = node0 + j;
        int r0 = rowptr[nodes[j]], r1 = rowptr[nodes[j] + 1];
        dgj[j] = r1 - r0;
        rbj[j] = use_lds ? (r0 - eb) : r0;
    }
    __syncthreads();

    // own input features (lane = c&3 map, replicated)
    float t1r[NPW], t0r[NPW], acc[NPW];
#pragma unroll
    for (int j = 0; j < NPW; j++) t1r[j] = x[nodes[j] * 4 + (lane & 3)];

    // k = 0
    stage_w(W1, lsW, CI * CO);
    float bv = b1[lane];
    __syncthreads();
#pragma unroll
    for (int j = 0; j < NPW; j++) { acc[j] = bv; t0r[j] = t1r[j]; }
    dense_step<CI, CO>(acc, t1r, lsW, lane);

    float* tb[2] = {t4a, t4b};
    int cur = 1;
    int eo = lane >> 2, lc4 = (lane & 3) * 4;

#pragma unroll 1
    for (int k = 1; k < K; k++) {
        __syncthreads();
        stage_w(W1 + k * CI * CO, lsW, CI * CO);
        const char* gs = (const char*)((k == 1) ? x : tb[cur]);
        float t2v[NPW];
#pragma unroll
        for (int j = 0; j < NPW; j++) {
            float agg = use_lds
                ? gather_n<true >(gs, ls_pr, g_pr, rbj[j], dgj[j], lc4, eo)
                : gather_n<false>(gs, ls_pr, g_pr, rbj[j], dgj[j], lc4, eo);
            t2v[j] = (k == 1) ? agg : fmaf(2.f, agg, -t0r[j]);
        }
        __syncthreads();
        dense_step<CI, CO>(acc, t2v, lsW, lane);
#pragma unroll
        for (int j = 0; j < NPW; j++) { t0r[j] = t1r[j]; t1r[j] = t2v[j]; }
        if (k < K - 1) {
            float* gd = tb[cur ^ 1];
#pragma unroll
            for (int j = 0; j < NPW; j++)
                if (lane < 4) ast(&gd[nodes[j] * 4 + lane], t2v[j]);
            cur ^= 1;
            gbar(bar);
        }
    }

    // epilogue: silu -> h1 (plain stores; kernel-end flush publishes)
#pragma unroll
    for (int j = 0; j < NPW; j++) {
        float a = acc[j];
        h1[nodes[j] * 64 + lane] = a / (1.f + expf(-a));
    }
}

// ---------------- k_wide (R3-proven): one wave per node ----------------
// MODE 1: fused k0+k1; MODE 2: recurrence. LAST 0: store; 1: silu->hout; 2: +layer4
template <int CI, int CO, int MODE, int LAST>
__global__ __launch_bounds__(256) void k_wide(
    const int* __restrict__ rowptr, const int2* __restrict__ pr,
    const float* __restrict__ hin,
    const float* __restrict__ t0, const float* __restrict__ t1,
    float* __restrict__ t2, float* __restrict__ accb,
    const float* __restrict__ Wk, const float* __restrict__ bias,
    const float* __restrict__ W4, float* __restrict__ outp)
{
    int tid = threadIdx.x;
    int lane = tid & 63;
    int node = blockIdx.x * 4 + (tid >> 6);
    int rb = rowptr[node];
    int dg = rowptr[node + 1] - rb;
    int lane4 = lane * 4;

    float acc, t2v;
    if (MODE == 1) {
        float hr = hin[node * 64 + lane];
        acc = (lane < CO) ? bias[lane] : 0.f;
        dense<CI, CO>(acc, hr, Wk, lane);
        t2v = gather_w((const char*)hin, pr, rb, dg, lane4);
        dense<CI, CO>(acc, t2v, Wk + CI * CO, lane);
    } else {
        acc = accb[node * 64 + lane];
        float t0r = t0[node * 64 + lane];
        float agg = gather_w((const char*)t1, pr, rb, dg, lane4);
        t2v = fmaf(2.f, agg, -t0r);
        dense<CI, CO>(acc, t2v, Wk, lane);
    }

    if (LAST == 0) {
        accb[node * 64 + lane] = acc;
        t2[node * 64 + lane] = t2v;
    } else if (LAST == 1) {
        outp[node * 64 + lane] = acc / (1.f + expf(-acc));
    } else {
        float h = acc / (1.f + expf(-acc));
        float w4 = (lane < 30) ? W4[lane] : 0.f;
        float p = h * w4;
        p += __shfl_xor(p, 1);
        p += __shfl_xor(p, 2);
        p += __shfl_xor(p, 4);
        p += __shfl_xor(p, 8);
        p += __shfl_xor(p, 16);
        p += __shfl_xor(p, 32);
        if (lane == 0) outp[node] = 1.f / (1.f + expf(-p));
    }
}

// ---------------- host ----------------
extern "C" void kernel_launch(void* const* d_in, const int* in_sizes, int n_in,
                              void* d_out, int out_size, void* d_ws, size_t ws_size,
                              hipStream_t stream) {
    const float* x  = (const float*)d_in[0];
    const int*   ei = (const int*)d_in[1];
    const float* ew = (const float*)d_in[2];
    const float* W1 = (const float*)d_in[3];
    const float* b1 = (const float*)d_in[4];
    const float* W2 = (const float*)d_in[5];
    const float* b2 = (const float*)d_in[6];
    const float* W3 = (const float*)d_in[7];
    const float* b3 = (const float*)d_in[8];
    const float* W4 = (const float*)d_in[9];
    float* out = (float*)d_out;

    const int n = N_NODES, E = N_EDGES;

    char* ws = (char*)d_ws;
    size_t off = 0;
    auto alloc = [&](size_t bytes) -> void* {
        void* p = ws + off;
        off += (bytes + 255) & ~(size_t)255;
        return p;
    };
    float* deg    = (float*)alloc(n * 4);
    int*   cnt    = (int*)alloc(n * 4);
    int*   fill   = (int*)alloc(n * 4);
    int*   rowptr = (int*)alloc((n + 4) * 4);
    float* normw  = (float*)alloc((size_t)E * 4);
    int2*  pr     = (int2*)alloc((size_t)E * 8);
    int*   bar    = (int*)alloc(128 * 4);
    float* t4a  = (float*)alloc(n * 4 * 4);
    float* t4b  = (float*)alloc(n * 4 * 4);
    float* tba  = (float*)alloc(n * 64 * 4);
    float* tbb  = (float*)alloc(n * 64 * 4);
    float* tbc  = (float*)alloc(n * 64 * 4);
    float* accb = (float*)alloc(n * 64 * 4);
    float* h1   = (float*)alloc(n * 64 * 4);
    float* h2   = (float*)alloc(n * 64 * 4);
    (void)ws_size; (void)n_in; (void)in_sizes; (void)out_size;

    // ---- preprocessing ----
    k_init<<<(n + 255) / 256, 256, 0, stream>>>(deg, cnt, fill, bar, n);
    k_deg <<<(E + 255) / 256, 256, 0, stream>>>(ei, ew, deg, E);
    k_dis <<<(n + 255) / 256, 256, 0, stream>>>(deg, n);
    k_norm<<<(E + 255) / 256, 256, 0, stream>>>(ei, ew, deg, normw, cnt, E);
    k_scan<<<1, 1024, 0, stream>>>(cnt, rowptr, n);
    k_fill<<<(E + 255) / 256, 256, 0, stream>>>(ei, normw, rowptr, fill, pr, E);

    // ---- Layer 1: persistent (119 in-kernel barriers) -> h1 ----
    layer1_persistent<<<GRID, BLOCK, 0, stream>>>(x, rowptr, pr, W1, b1,
                                                  t4a, t4b, h1, bar);

    const int G = n / 4;  // 2500 blocks x 256 threads, one wave per node

    // ---- Layer 2: K=120, 64 -> 60, silu -> h2 ----
    {
        const int K = 120;
        float* tb[3] = {tba, tbb, tbc};
        k_wide<64, 60, 1, 0><<<G, 256, 0, stream>>>(rowptr, pr, h1, nullptr, nullptr,
                                                    tb[1], accb, W2, b2, nullptr, nullptr);
        for (int k = 2; k < K; k++) {
            const float* t0p = (k == 2) ? h1 : tb[(k - 2) % 3];
            const float* t1p = tb[(k - 1) % 3];
            const float* Wk = W2 + (size_t)k * 64 * 60;
            if (k < K - 1)
                k_wide<64, 60, 2, 0><<<G, 256, 0, stream>>>(rowptr, pr, nullptr, t0p, t1p,
                                                            tb[k % 3], accb, Wk, nullptr,
                                                            nullptr, nullptr);
            else
                k_wide<64, 60, 2, 1><<<G, 256, 0, stream>>>(rowptr, pr, nullptr, t0p, t1p,
                                                            nullptr, accb, Wk, nullptr,
                                                            nullptr, h2);
        }
    }

    // ---- Layer 3 (K=20, 60 -> 30, silu) + fused Layer 4 (30 -> 1, sigmoid) ----
    {
        const int K = 20;
        float* tb[3] = {tba, tbb, tbc};
        k_wide<60, 30, 1, 0><<<G, 256, 0, stream>>>(rowptr, pr, h2, nullptr, nullptr,
                                                    tb[1], accb, W3, b3, nullptr, nullptr);
        for (int k = 2; k < K; k++) {
            const float* t0p = (k == 2) ? h2 : tb[(k - 2) % 3];
            const float* t1p = tb[(k - 1) % 3];
            const float* Wk = W3 + (size_t)k * 60 * 30;
            if (k < K - 1)
                k_wide<60, 30, 2, 0><<<G, 256, 0, stream>>>(rowptr, pr, nullptr, t0p, t1p,
                                                            tb[k % 3], accb, Wk, nullptr,
                                                            nullptr, nullptr);
            else
                k_wide<60, 30, 2, 2><<<G, 256, 0, stream>>>(rowptr, pr, nullptr, t0p, t1p,
                                                            nullptr, accb, Wk, nullptr,
                                                            W4, out);
        }
    }
}